// Round 1
// baseline (196.777 us; speedup 1.0000x reference)
//
#include <hip/hip_runtime.h>
#include <math.h>

#define NWL   112
#define NCOLS 111          // END - START = 111 usable columns
#define NATM  84
#define THREADS 256
#define WAVES_PER_BLOCK 4
#define MAIN_BLOCKS 2048

__device__ __forceinline__ float half_reduce_sum(float v) {
    // butterfly within each 32-lane half of the wave (xor offs <=16 never
    // cross the 32-lane boundary on wave64)
    v += __shfl_xor(v, 1,  64);
    v += __shfl_xor(v, 2,  64);
    v += __shfl_xor(v, 4,  64);
    v += __shfl_xor(v, 8,  64);
    v += __shfl_xor(v, 16, 64);
    return v;
}

__device__ __forceinline__ float wave_reduce_sum(float v) {
#pragma unroll
    for (int off = 32; off >= 1; off >>= 1)
        v += __shfl_xor(v, off, 64);
    return v;
}

__global__ __launch_bounds__(THREADS) void wfa_main(
    const float* __restrict__ stokes,   // (B, 4, 112)
    const float* __restrict__ pred,     // (B, 84)
    const float* __restrict__ targ,     // (B, 84)
    const float* __restrict__ wl,       // (112)
    float* __restrict__ ws,             // [nblk] base | [nblk] wfa | [nblk] cnt
    int nrows, int nblocks)
{
    __shared__ float s_idw[NWL];                  // 1/grad(wl), s_idw[111]=0 (excluded col)
    __shared__ float s_red[WAVES_PER_BLOCK][3];

    const int tid  = threadIdx.x;
    const int lane = tid & 63;
    const int wid  = tid >> 6;
    const int sub  = lane & 31;       // position within half-wave
    const int g    = lane & 32;       // half base (0 or 32)

    // grad(wl) over the truncated 111-col array, per reference _np_gradient.
    // float32 cancellation makes dwl vary ~1% per j: must use actual wl input.
    if (tid < NWL) {
        const int j = tid;
        float d;
        if (j == 0)              d = wl[1] - wl[0];
        else if (j == NCOLS - 1) d = wl[NCOLS - 1] - wl[NCOLS - 2];
        else if (j < NCOLS - 1)  d = 0.5f * (wl[j + 1] - wl[j - 1]);
        else                     d = 1.0f;                 // j==111 (excluded)
        s_idw[j] = (j == NCOLS) ? 0.0f : 1.0f / d;
    }
    __syncthreads();

    // per-lane gradient scale, loaded ONCE (constant across rows)
    float4 idw4 = make_float4(0.f, 0.f, 0.f, 0.f);
    if (sub < 28) idw4 = *(const float4*)&s_idw[4 * sub];

    const float WFA_DEN = (float)(4.6686e-13 * 6301.5 * 6301.5 * 1.5);

    // one row per HALF-wave
    const int h  = (blockIdx.x * WAVES_PER_BLOCK + wid) * 2 + (lane >> 5);
    const int nh = nblocks * WAVES_PER_BLOCK * 2;

    float base_acc = 0.f;
    float wfa_acc  = 0.f;   // sub==0 lanes only
    float cnt_acc  = 0.f;

    for (int r = h; r < nrows; r += nh) {
        const float* rowbase = stokes + (size_t)r * (4 * NWL);

        float4 I4 = make_float4(0.f, 0.f, 0.f, 0.f);
        float4 V4 = make_float4(0.f, 0.f, 0.f, 0.f);
        if (sub < 28) {
            I4 = ((const float4*)rowbase)[sub];                 // ch 0
            V4 = ((const float4*)(rowbase + 3 * NWL))[sub];     // ch 3
        }

        float4 P4 = make_float4(0.f, 0.f, 0.f, 0.f);
        float bpart = 0.f;
        if (sub < 21) {
            P4 = ((const float4*)(pred + (size_t)r * NATM))[sub];
            const float4 T4 = ((const float4*)(targ + (size_t)r * NATM))[sub];
            bpart = fabsf(P4.x - T4.x) + fabsf(P4.y - T4.y)
                  + fabsf(P4.z - T4.z) + fabsf(P4.w - T4.w);
        }
        base_acc += bpart;

        // gradient neighbors from adjacent lanes (no LDS round-trip)
        const int lm1 = lane - (sub ? 1 : 0);
        const float im1 = __shfl(I4.w, lm1, 64);       // I[4*sub - 1]
        const float ip4 = __shfl(I4.x, lane + 1, 64);  // I[4*sub + 4] (lane g+28 holds 0)

        // np.gradient numerators; j = 4*sub + c
        const float n0 = (sub == 0)  ? (I4.y - I4.x) : 0.5f * (I4.y - im1);
        const float n1 = 0.5f * (I4.z - I4.x);
        const float n2 = (sub == 27) ? (I4.z - I4.y) : 0.5f * (I4.w - I4.y);
        const float n3 = 0.5f * (ip4 - I4.z);          // j=111 killed by idw4.w=0

        const float d0 = n0 * idw4.x;
        const float d1 = n1 * idw4.y;
        const float d2 = n2 * idw4.z;
        const float d3 = n3 * idw4.w;
        const float v3 = (sub == 27) ? 0.f : V4.w;     // col 111 excluded from sums

        float sd  = d0 + d1 + d2 + d3;
        float sdd = fmaf(d0, d0, fmaf(d1, d1, fmaf(d2, d2, d3 * d3)));
        float sdv = fmaf(d0, V4.x, fmaf(d1, V4.y, fmaf(d2, V4.z, d3 * v3)));
        float sv  = V4.x + V4.y + V4.z + v3;

        sd  = half_reduce_sum(sd);
        sdd = half_reduce_sum(sdd);
        sdv = half_reduce_sum(sdv);
        sv  = half_reduce_sum(sv);

        // a[3],a[7],a[11] = P4.w of sub 0,1,2 in this half
        const float a7  = __shfl(P4.w, g | 1, 64);
        const float a11 = __shfl(P4.w, g | 2, 64);

        if (sub == 0) {
            const float n  = (float)NCOLS;
            const float p0 = (n * sdv - sd * sv) / (n * sdd - sd * sd);
            const float ab = fabsf(p0) / WFA_DEN;      // |wfa_blos|
            if (ab < 100.0f) {
                const float pb = (P4.w + a7 + a11) / 3.0f;
                wfa_acc += fabsf(log10f(fabsf(pb) + 1e-10f) - log10f(ab + 1e-10f));
                cnt_acc += 1.0f;
            }
        }
    }

    base_acc = wave_reduce_sum(base_acc);
    wfa_acc  = wave_reduce_sum(wfa_acc);   // nonzero only on lanes 0,32
    cnt_acc  = wave_reduce_sum(cnt_acc);
    if (lane == 0) {
        s_red[wid][0] = base_acc;
        s_red[wid][1] = wfa_acc;
        s_red[wid][2] = cnt_acc;
    }
    __syncthreads();
    if (tid == 0) {
        float b = 0.f, w = 0.f, c = 0.f;
#pragma unroll
        for (int k = 0; k < WAVES_PER_BLOCK; ++k) {
            b += s_red[k][0]; w += s_red[k][1]; c += s_red[k][2];
        }
        ws[blockIdx.x]               = b;
        ws[nblocks + blockIdx.x]     = w;
        ws[2 * nblocks + blockIdx.x] = c;
    }
}

__global__ __launch_bounds__(256) void wfa_final(
    const float* __restrict__ ws, float* __restrict__ out,
    int nblocks, int nrows)
{
    const int tid = threadIdx.x;
    float b = 0.f, w = 0.f, c = 0.f;
    for (int i = tid; i < nblocks; i += 256) {
        b += ws[i];
        w += ws[nblocks + i];
        c += ws[2 * nblocks + i];
    }
    b = wave_reduce_sum(b);
    w = wave_reduce_sum(w);
    c = wave_reduce_sum(c);

    __shared__ float sb[4], sw[4], sc[4];
    const int lane = tid & 63, wid = tid >> 6;
    if (lane == 0) { sb[wid] = b; sw[wid] = w; sc[wid] = c; }
    __syncthreads();
    if (tid == 0) {
        const float B_ = sb[0] + sb[1] + sb[2] + sb[3];
        const float W_ = sw[0] + sw[1] + sw[2] + sw[3];
        const float C_ = sc[0] + sc[1] + sc[2] + sc[3];
        const float base_loss = B_ / (float)((long long)nrows * NATM);
        const float wfa_ml    = W_ / fmaxf(C_, 1.0f);
        const bool  apply     = (base_loss < 0.0004f) && (C_ > 0.f);
        out[0] = apply ? (0.5f * base_loss + 0.5f * wfa_ml) : base_loss;
        out[1] = base_loss;
        out[2] = apply ? wfa_ml : 0.f;
    }
}

extern "C" void kernel_launch(void* const* d_in, const int* in_sizes, int n_in,
                              void* d_out, int out_size, void* d_ws, size_t ws_size,
                              hipStream_t stream)
{
    const float* stokes = (const float*)d_in[0];
    const float* pred   = (const float*)d_in[1];
    const float* targ   = (const float*)d_in[2];
    const float* wl     = (const float*)d_in[3];
    float* out = (float*)d_out;
    float* ws  = (float*)d_ws;

    const int nrows = in_sizes[1] / NATM;   // 65536

    int nblocks = MAIN_BLOCKS;
    const size_t need = (size_t)nblocks * 3 * sizeof(float);
    if (ws_size < need) {
        nblocks = (int)(ws_size / (3 * sizeof(float)));
        if (nblocks < 1) nblocks = 1;
    }

    hipLaunchKernelGGL(wfa_main, dim3(nblocks), dim3(THREADS), 0, stream,
                       stokes, pred, targ, wl, ws, nrows, nblocks);
    hipLaunchKernelGGL(wfa_final, dim3(1), dim3(256), 0, stream,
                       ws, out, nblocks, nrows);
}

// Round 2
// 186.628 us; speedup vs baseline: 1.0544x; 1.0544x over previous
//
#include <hip/hip_runtime.h>
#include <math.h>

#define NWL   112
#define NCOLS 111          // END - START = 111 usable columns
#define NATM  84
#define THREADS 256
#define WAVES_PER_BLOCK 4
#define MAIN_BLOCKS 2048

typedef float f4v __attribute__((ext_vector_type(4)));

// ---- bit-exact xor-butterfly steps ----------------------------------------
// DPP where an exact xor-equivalent control exists (VALU pipe, ~4cy):
//   xor1 == quad_perm [1,0,3,2]  = 0xB1
//   xor2 == quad_perm [2,3,0,1]  = 0x4E
//   xor8 == row_ror:8 (i+8 mod 16 == i^8 for all i in 0..15) = 0x128
// ds_swizzle (imm pattern, no addr VGPR) for xor4 / xor16 (DS pipe, ~30cy):
//   bit-mode offset = (xor<<10)|0x1F : xor4 = 0x101F, xor16 = 0x401F
template<int CTRL>
__device__ __forceinline__ float dpp_add(float v) {
    int x = __builtin_amdgcn_update_dpp(0, __float_as_int(v), CTRL, 0xF, 0xF, true);
    return v + __int_as_float(x);
}
template<int PAT>
__device__ __forceinline__ float swz_add(float v) {
    int x = __builtin_amdgcn_ds_swizzle(__float_as_int(v), PAT);
    return v + __int_as_float(x);
}

// sum across each 32-lane half of the wave; identical pairing order to the
// previous __shfl_xor(1,2,4,8,16) chain -> bit-exact results
__device__ __forceinline__ float half_reduce_sum(float v) {
    v = dpp_add<0xB1>(v);      // ^1
    v = dpp_add<0x4E>(v);      // ^2
    v = swz_add<0x101F>(v);    // ^4
    v = dpp_add<0x128>(v);     // ^8
    v = swz_add<0x401F>(v);    // ^16
    return v;
}

__device__ __forceinline__ float wave_reduce_sum(float v) {
#pragma unroll
    for (int off = 32; off >= 1; off >>= 1)
        v += __shfl_xor(v, off, 64);
    return v;
}

__global__ __launch_bounds__(THREADS) void wfa_main(
    const float* __restrict__ stokes,   // (B, 4, 112)
    const float* __restrict__ pred,     // (B, 84)
    const float* __restrict__ targ,     // (B, 84)
    const float* __restrict__ wl,       // (112)
    float* __restrict__ ws,             // [nblk] base | [nblk] wfa | [nblk] cnt
    int nrows, int nblocks)
{
    __shared__ float s_idw[NWL];                  // 1/grad(wl), s_idw[111]=0 (excluded col)
    __shared__ float s_red[WAVES_PER_BLOCK][3];

    const int tid  = threadIdx.x;
    const int lane = tid & 63;
    const int wid  = tid >> 6;
    const int sub  = lane & 31;       // position within half-wave
    const int g    = lane & 32;       // half base (0 or 32)

    // grad(wl) over the truncated 111-col array, per reference _np_gradient.
    // float32 cancellation makes dwl vary ~1% per j: must use actual wl input.
    if (tid < NWL) {
        const int j = tid;
        float d;
        if (j == 0)              d = wl[1] - wl[0];
        else if (j == NCOLS - 1) d = wl[NCOLS - 1] - wl[NCOLS - 2];
        else if (j < NCOLS - 1)  d = 0.5f * (wl[j + 1] - wl[j - 1]);
        else                     d = 1.0f;                 // j==111 (excluded)
        s_idw[j] = (j == NCOLS) ? 0.0f : 1.0f / d;
    }
    __syncthreads();

    // per-lane gradient scale, loaded ONCE (constant across rows)
    float4 idw4 = make_float4(0.f, 0.f, 0.f, 0.f);
    if (sub < 28) idw4 = *(const float4*)&s_idw[4 * sub];

    const float WFA_DEN = (float)(4.6686e-13 * 6301.5 * 6301.5 * 1.5);

    // one row per HALF-wave
    const int h  = (blockIdx.x * WAVES_PER_BLOCK + wid) * 2 + (lane >> 5);
    const int nh = nblocks * WAVES_PER_BLOCK * 2;

    float base_acc = 0.f;
    float wfa_acc  = 0.f;   // sub==0 lanes only
    float cnt_acc  = 0.f;

    for (int r = h; r < nrows; r += nh) {
        const float* rowbase = stokes + (size_t)r * (4 * NWL);

        float4 I4 = make_float4(0.f, 0.f, 0.f, 0.f);
        float4 V4 = make_float4(0.f, 0.f, 0.f, 0.f);
        if (sub < 28) {
            f4v iv = __builtin_nontemporal_load((const f4v*)rowbase + sub);          // ch 0
            f4v vv = __builtin_nontemporal_load((const f4v*)(rowbase + 3 * NWL) + sub); // ch 3
            I4 = make_float4(iv.x, iv.y, iv.z, iv.w);
            V4 = make_float4(vv.x, vv.y, vv.z, vv.w);
        }

        float4 P4 = make_float4(0.f, 0.f, 0.f, 0.f);
        float bpart = 0.f;
        if (sub < 21) {
            f4v pv = __builtin_nontemporal_load((const f4v*)(pred + (size_t)r * NATM) + sub);
            f4v tv = __builtin_nontemporal_load((const f4v*)(targ + (size_t)r * NATM) + sub);
            P4 = make_float4(pv.x, pv.y, pv.z, pv.w);
            bpart = fabsf(pv.x - tv.x) + fabsf(pv.y - tv.y)
                  + fabsf(pv.z - tv.z) + fabsf(pv.w - tv.w);
        }
        base_acc += bpart;

        // independent gathers issued early so their DS latency overlaps the
        // reduction chains below
        const int lm1 = lane - (sub ? 1 : 0);
        const float im1 = __shfl(I4.w, lm1, 64);       // I[4*sub - 1]
        const float ip4 = __shfl(I4.x, lane + 1, 64);  // I[4*sub + 4] (lane g+28 holds 0)
        const float a7  = __shfl(P4.w, g | 1, 64);     // a[7]
        const float a11 = __shfl(P4.w, g | 2, 64);     // a[11]

        // np.gradient numerators; j = 4*sub + c
        const float n0 = (sub == 0)  ? (I4.y - I4.x) : 0.5f * (I4.y - im1);
        const float n1 = 0.5f * (I4.z - I4.x);
        const float n2 = (sub == 27) ? (I4.z - I4.y) : 0.5f * (I4.w - I4.y);
        const float n3 = 0.5f * (ip4 - I4.z);          // j=111 killed by idw4.w=0

        const float d0 = n0 * idw4.x;
        const float d1 = n1 * idw4.y;
        const float d2 = n2 * idw4.z;
        const float d3 = n3 * idw4.w;
        const float v3 = (sub == 27) ? 0.f : V4.w;     // col 111 excluded from sums

        float sd  = d0 + d1 + d2 + d3;
        float sdd = fmaf(d0, d0, fmaf(d1, d1, fmaf(d2, d2, d3 * d3)));
        float sdv = fmaf(d0, V4.x, fmaf(d1, V4.y, fmaf(d2, V4.z, d3 * v3)));
        float sv  = V4.x + V4.y + V4.z + v3;

        sd  = half_reduce_sum(sd);
        sdd = half_reduce_sum(sdd);
        sdv = half_reduce_sum(sdv);
        sv  = half_reduce_sum(sv);

        if (sub == 0) {
            const float n  = (float)NCOLS;
            const float p0 = (n * sdv - sd * sv) / (n * sdd - sd * sd);
            const float ab = fabsf(p0) / WFA_DEN;      // |wfa_blos|
            if (ab < 100.0f) {
                const float pb = (P4.w + a7 + a11) / 3.0f;
                wfa_acc += fabsf(log10f(fabsf(pb) + 1e-10f) - log10f(ab + 1e-10f));
                cnt_acc += 1.0f;
            }
        }
    }

    base_acc = wave_reduce_sum(base_acc);
    wfa_acc  = wave_reduce_sum(wfa_acc);   // nonzero only on lanes 0,32
    cnt_acc  = wave_reduce_sum(cnt_acc);
    if (lane == 0) {
        s_red[wid][0] = base_acc;
        s_red[wid][1] = wfa_acc;
        s_red[wid][2] = cnt_acc;
    }
    __syncthreads();
    if (tid == 0) {
        float b = 0.f, w = 0.f, c = 0.f;
#pragma unroll
        for (int k = 0; k < WAVES_PER_BLOCK; ++k) {
            b += s_red[k][0]; w += s_red[k][1]; c += s_red[k][2];
        }
        ws[blockIdx.x]               = b;
        ws[nblocks + blockIdx.x]     = w;
        ws[2 * nblocks + blockIdx.x] = c;
    }
}

__global__ __launch_bounds__(256) void wfa_final(
    const float* __restrict__ ws, float* __restrict__ out,
    int nblocks, int nrows)
{
    const int tid = threadIdx.x;
    float b = 0.f, w = 0.f, c = 0.f;
    for (int i = tid; i < nblocks; i += 256) {
        b += ws[i];
        w += ws[nblocks + i];
        c += ws[2 * nblocks + i];
    }
    b = wave_reduce_sum(b);
    w = wave_reduce_sum(w);
    c = wave_reduce_sum(c);

    __shared__ float sb[4], sw[4], sc[4];
    const int lane = tid & 63, wid = tid >> 6;
    if (lane == 0) { sb[wid] = b; sw[wid] = w; sc[wid] = c; }
    __syncthreads();
    if (tid == 0) {
        const float B_ = sb[0] + sb[1] + sb[2] + sb[3];
        const float W_ = sw[0] + sw[1] + sw[2] + sw[3];
        const float C_ = sc[0] + sc[1] + sc[2] + sc[3];
        const float base_loss = B_ / (float)((long long)nrows * NATM);
        const float wfa_ml    = W_ / fmaxf(C_, 1.0f);
        const bool  apply     = (base_loss < 0.0004f) && (C_ > 0.f);
        out[0] = apply ? (0.5f * base_loss + 0.5f * wfa_ml) : base_loss;
        out[1] = base_loss;
        out[2] = apply ? wfa_ml : 0.f;
    }
}

extern "C" void kernel_launch(void* const* d_in, const int* in_sizes, int n_in,
                              void* d_out, int out_size, void* d_ws, size_t ws_size,
                              hipStream_t stream)
{
    const float* stokes = (const float*)d_in[0];
    const float* pred   = (const float*)d_in[1];
    const float* targ   = (const float*)d_in[2];
    const float* wl     = (const float*)d_in[3];
    float* out = (float*)d_out;
    float* ws  = (float*)d_ws;

    const int nrows = in_sizes[1] / NATM;   // 65536

    int nblocks = MAIN_BLOCKS;
    const size_t need = (size_t)nblocks * 3 * sizeof(float);
    if (ws_size < need) {
        nblocks = (int)(ws_size / (3 * sizeof(float)));
        if (nblocks < 1) nblocks = 1;
    }

    hipLaunchKernelGGL(wfa_main, dim3(nblocks), dim3(THREADS), 0, stream,
                       stokes, pred, targ, wl, ws, nrows, nblocks);
    hipLaunchKernelGGL(wfa_final, dim3(1), dim3(256), 0, stream,
                       ws, out, nblocks, nrows);
}